// Round 1
// baseline (879.273 us; speedup 1.0000x reference)
//
#include <hip/hip_runtime.h>
#include <hip/hip_bf16.h>

#define NH 16
#define NKV 4
#define HD 128
#define ATT_SCALE 0.08838834764831845f

using bf16x8 = __attribute__((ext_vector_type(8))) __bf16;
using f32x4  = __attribute__((ext_vector_type(4))) float;
using u16x8  = __attribute__((ext_vector_type(8))) unsigned short;
using u16x2  = __attribute__((ext_vector_type(2))) unsigned short;

__device__ __forceinline__ unsigned short f2b(float f) {
  __hip_bfloat16 h = __float2bfloat16(f);
  return __builtin_bit_cast(unsigned short, h);
}
__device__ __forceinline__ float b2f(unsigned short u) {
  unsigned int v = ((unsigned int)u) << 16;
  return __builtin_bit_cast(float, v);
}

// ---------------- fp32 -> bf16 conversion (8 elems/thread) ----------------
__global__ __launch_bounds__(256) void cvt_kernel(const float* __restrict__ src,
                                                  unsigned short* __restrict__ dst, int n8) {
  int i = blockIdx.x * 256 + threadIdx.x;
  if (i >= n8) return;
  const float4* s4 = reinterpret_cast<const float4*>(src) + (size_t)i * 2;
  float4 v0 = s4[0], v1 = s4[1];
  u16x8 o;
  o[0] = f2b(v0.x); o[1] = f2b(v0.y); o[2] = f2b(v0.z); o[3] = f2b(v0.w);
  o[4] = f2b(v1.x); o[5] = f2b(v1.y); o[6] = f2b(v1.z); o[7] = f2b(v1.w);
  reinterpret_cast<u16x8*>(dst)[i] = o;
}

// ---------------- GEMM: C[M,N] = A[M,K] * B[N,K]^T  (bf16 in, f32 acc) -----
// tile 128x128, K-step 32, 4 waves in 2x2, each wave 64x64 (4x4 frags)
template<int CF32>
__global__ __launch_bounds__(256) void gemm_bt(const unsigned short* __restrict__ A,
                                               const unsigned short* __restrict__ B,
                                               void* __restrict__ C,
                                               int M, int N, int K) {
  __shared__ unsigned short As[128][40];
  __shared__ unsigned short Bs[128][40];
  const int tid = threadIdx.x;
  const int lane = tid & 63;
  const int wid = tid >> 6;
  const int wm = wid >> 1, wn = wid & 1;
  const int row0 = blockIdx.y * 128, col0 = blockIdx.x * 128;
  const int srow = tid >> 1;
  const int scol = (tid & 1) * 16;
  const unsigned short* Ag = A + (size_t)(row0 + srow) * K + scol;
  const unsigned short* Bg = B + (size_t)(col0 + srow) * K + scol;
  const int fr = lane & 15;
  const int fk = (lane >> 4) * 8;

  f32x4 acc[4][4];
#pragma unroll
  for (int i = 0; i < 4; i++)
#pragma unroll
    for (int j = 0; j < 4; j++) acc[i][j] = f32x4{0.f, 0.f, 0.f, 0.f};

  for (int k0 = 0; k0 < K; k0 += 32) {
    u16x8 a0 = *reinterpret_cast<const u16x8*>(Ag + k0);
    u16x8 a1 = *reinterpret_cast<const u16x8*>(Ag + k0 + 8);
    u16x8 b0 = *reinterpret_cast<const u16x8*>(Bg + k0);
    u16x8 b1 = *reinterpret_cast<const u16x8*>(Bg + k0 + 8);
    __syncthreads();
    *reinterpret_cast<u16x8*>(&As[srow][scol])     = a0;
    *reinterpret_cast<u16x8*>(&As[srow][scol + 8]) = a1;
    *reinterpret_cast<u16x8*>(&Bs[srow][scol])     = b0;
    *reinterpret_cast<u16x8*>(&Bs[srow][scol + 8]) = b1;
    __syncthreads();
    bf16x8 af[4], bfr[4];
#pragma unroll
    for (int i = 0; i < 4; i++)
      af[i] = *reinterpret_cast<const bf16x8*>(&As[wm * 64 + i * 16 + fr][fk]);
#pragma unroll
    for (int i = 0; i < 4; i++)
      bfr[i] = *reinterpret_cast<const bf16x8*>(&Bs[wn * 64 + i * 16 + fr][fk]);
#pragma unroll
    for (int i = 0; i < 4; i++)
#pragma unroll
      for (int j = 0; j < 4; j++)
        acc[i][j] = __builtin_amdgcn_mfma_f32_16x16x32_bf16(af[i], bfr[j], acc[i][j], 0, 0, 0);
  }

  const int r4 = (lane >> 4) * 4;
#pragma unroll
  for (int i = 0; i < 4; i++) {
#pragma unroll
    for (int j = 0; j < 4; j++) {
      int rb = row0 + wm * 64 + i * 16 + r4;
      int cb = col0 + wn * 64 + j * 16 + fr;
#pragma unroll
      for (int r = 0; r < 4; r++) {
        if (CF32)
          reinterpret_cast<float*>(C)[(size_t)(rb + r) * N + cb] = acc[i][j][r];
        else
          reinterpret_cast<unsigned short*>(C)[(size_t)(rb + r) * N + cb] = f2b(acc[i][j][r]);
      }
    }
  }
}

// ---------------- RoPE: q_lin/k_lin -> q_rope[B][H][S][D], k_rope[B][KVH][S][D], new_k f32
__global__ __launch_bounds__(256) void rope_kernel(const unsigned short* __restrict__ qlin,
                                                   const unsigned short* __restrict__ klin,
                                                   const float* __restrict__ freqs,
                                                   unsigned short* __restrict__ qro,
                                                   unsigned short* __restrict__ kro,
                                                   float* __restrict__ newk) {
  const int NQ = 4096 * 16 * 64;
  const int NK = 4096 * 4 * 64;
  int idx = blockIdx.x * 256 + threadIdx.x;
  if (idx >= NQ + NK) return;
  if (idx < NQ) {
    int i = idx & 63;
    int h = (idx >> 6) & 15;
    int row = idx >> 10;             // b*2048 + s
    int s = row & 2047, b = row >> 11;
    float f = freqs[s * 64 + i];
    float c = cosf(f), sn = sinf(f);
    u16x2 xv = *reinterpret_cast<const u16x2*>(qlin + (size_t)row * 2048 + h * 128 + 2 * i);
    float x1 = b2f(xv.x), x2 = b2f(xv.y);
    float r1 = x1 * c - x2 * sn;
    float r2 = x1 * sn + x2 * c;
    u16x2 o; o.x = f2b(r1); o.y = f2b(r2);
    *reinterpret_cast<u16x2*>(qro + ((size_t)(b * 16 + h) * 2048 + s) * 128 + 2 * i) = o;
  } else {
    idx -= NQ;
    int i = idx & 63;
    int h = (idx >> 6) & 3;
    int row = idx >> 8;
    int s = row & 2047, b = row >> 11;
    float f = freqs[s * 64 + i];
    float c = cosf(f), sn = sinf(f);
    u16x2 xv = *reinterpret_cast<const u16x2*>(klin + (size_t)row * 512 + h * 128 + 2 * i);
    float x1 = b2f(xv.x), x2 = b2f(xv.y);
    float r1 = x1 * c - x2 * sn;
    float r2 = x1 * sn + x2 * c;
    u16x2 o; o.x = f2b(r1); o.y = f2b(r2);
    *reinterpret_cast<u16x2*>(kro + ((size_t)(b * 4 + h) * 2048 + s) * 128 + 2 * i) = o;
    float2 of; of.x = r1; of.y = r2;
    *reinterpret_cast<float2*>(newk + (size_t)row * 512 + h * 128 + 2 * i) = of;
  }
}

// ---------------- V: copy to f32 out + transpose to vt[B][KVH][D][S] ------
__global__ __launch_bounds__(256) void vtrans_kernel(const unsigned short* __restrict__ vlin,
                                                     unsigned short* __restrict__ vt,
                                                     float* __restrict__ newv) {
  int idx = blockIdx.x * 256 + threadIdx.x;   // 2*2048*512
  if (idx >= 2 * 2048 * 512) return;
  int c = idx & 511, row = idx >> 9;
  int s = row & 2047, b = row >> 11;
  int kvh = c >> 7, d = c & 127;
  unsigned short u = vlin[idx];
  newv[idx] = b2f(u);
  vt[(size_t)((b * 4 + kvh) * 128 + d) * 2048 + s] = u;
}

// ---------------- flash attention, causal, GQA ----------------------------
// grid (S/64, H, B), 4 waves; wave owns 16 q-rows; KV tile 32
__global__ __launch_bounds__(256) void attn_kernel(const unsigned short* __restrict__ qro,
                                                   const unsigned short* __restrict__ kro,
                                                   const unsigned short* __restrict__ vt,
                                                   unsigned short* __restrict__ out) {
  __shared__ unsigned short Pl[4][16][40];
  const int tid = threadIdx.x, lane = tid & 63, w = tid >> 6;
  const int qt = blockIdx.x, h = blockIdx.y, b = blockIdx.z;
  const int kvh = h >> 2;
  const int qbase = qt * 64 + w * 16;
  const int fr = lane & 15, fg = lane >> 4, fk = (lane >> 4) * 8;
  const unsigned short* Qp = qro + ((size_t)(b * 16 + h) * 2048 + qbase) * 128;
  const unsigned short* Kp = kro + ((size_t)(b * 4 + kvh) * 2048) * 128;
  const unsigned short* Vp = vt + ((size_t)(b * 4 + kvh) * 128) * 2048;

  bf16x8 qf[4];
#pragma unroll
  for (int kk = 0; kk < 4; kk++)
    qf[kk] = *reinterpret_cast<const bf16x8*>(Qp + fr * 128 + kk * 32 + fk);

  f32x4 o[8];
#pragma unroll
  for (int dt = 0; dt < 8; dt++) o[dt] = f32x4{0.f, 0.f, 0.f, 0.f};
  float m[4] = {-1e30f, -1e30f, -1e30f, -1e30f};
  float sden[4] = {0.f, 0.f, 0.f, 0.f};

  const int nkv = qt * 64 + 64;   // uniform across the block (barrier-safe)
  for (int kv0 = 0; kv0 < nkv; kv0 += 32) {
    const bool active = (kv0 <= qbase + 15);
    f32x4 sc0 = f32x4{0.f, 0.f, 0.f, 0.f};
    f32x4 sc1 = f32x4{0.f, 0.f, 0.f, 0.f};
    float fac[4];
    if (active) {
#pragma unroll
      for (int kk = 0; kk < 4; kk++) {
        bf16x8 k0 = *reinterpret_cast<const bf16x8*>(Kp + (size_t)(kv0 + fr) * 128 + kk * 32 + fk);
        bf16x8 k1 = *reinterpret_cast<const bf16x8*>(Kp + (size_t)(kv0 + 16 + fr) * 128 + kk * 32 + fk);
        sc0 = __builtin_amdgcn_mfma_f32_16x16x32_bf16(qf[kk], k0, sc0, 0, 0, 0);
        sc1 = __builtin_amdgcn_mfma_f32_16x16x32_bf16(qf[kk], k1, sc1, 0, 0, 0);
      }
#pragma unroll
      for (int r = 0; r < 4; r++) {
        int qrow = qbase + fg * 4 + r;
        float s0 = sc0[r] * ATT_SCALE; if (kv0 + fr > qrow) s0 = -1e30f;
        float s1 = sc1[r] * ATT_SCALE; if (kv0 + 16 + fr > qrow) s1 = -1e30f;
        float pm = fmaxf(s0, s1);
        pm = fmaxf(pm, __shfl_xor(pm, 1));
        pm = fmaxf(pm, __shfl_xor(pm, 2));
        pm = fmaxf(pm, __shfl_xor(pm, 4));
        pm = fmaxf(pm, __shfl_xor(pm, 8));
        float mn = fmaxf(m[r], pm);
        fac[r] = expf(m[r] - mn);
        s0 = expf(s0 - mn);
        s1 = expf(s1 - mn);
        float ps = s0 + s1;
        ps += __shfl_xor(ps, 1);
        ps += __shfl_xor(ps, 2);
        ps += __shfl_xor(ps, 4);
        ps += __shfl_xor(ps, 8);
        sden[r] = sden[r] * fac[r] + ps;
        m[r] = mn;
        sc0[r] = s0; sc1[r] = s1;
      }
#pragma unroll
      for (int dt = 0; dt < 8; dt++) {
        f32x4 t = o[dt];
        t[0] *= fac[0]; t[1] *= fac[1]; t[2] *= fac[2]; t[3] *= fac[3];
        o[dt] = t;
      }
    }
    __syncthreads();   // WAR: previous iter's P reads done before overwrite
    if (active) {
#pragma unroll
      for (int r = 0; r < 4; r++) {
        Pl[w][fg * 4 + r][fr]      = f2b(sc0[r]);
        Pl[w][fg * 4 + r][16 + fr] = f2b(sc1[r]);
      }
    }
    __syncthreads();   // make P visible
    if (active) {
      bf16x8 pf = *reinterpret_cast<const bf16x8*>(&Pl[w][fr][fk]);
#pragma unroll
      for (int dt = 0; dt < 8; dt++) {
        bf16x8 vf = *reinterpret_cast<const bf16x8*>(Vp + (size_t)(dt * 16 + fr) * 2048 + kv0 + fk);
        o[dt] = __builtin_amdgcn_mfma_f32_16x16x32_bf16(pf, vf, o[dt], 0, 0, 0);
      }
    }
  }

#pragma unroll
  for (int r = 0; r < 4; r++) {
    float inv = 1.0f / sden[r];
    int qrow = qbase + fg * 4 + r;
    size_t rowoff = ((size_t)b * 2048 + qrow) * 2048 + (size_t)h * 128;
#pragma unroll
    for (int dt = 0; dt < 8; dt++)
      out[rowoff + dt * 16 + fr] = f2b(o[dt][r] * inv);
  }
}

// ---------------- launch ---------------------------------------------------
extern "C" void kernel_launch(void* const* d_in, const int* in_sizes, int n_in,
                              void* d_out, int out_size, void* d_ws, size_t ws_size,
                              hipStream_t stream) {
  const float* x  = (const float*)d_in[0];
  const float* wq = (const float*)d_in[1];
  const float* wk = (const float*)d_in[2];
  const float* wv = (const float*)d_in[3];
  const float* wo = (const float*)d_in[4];
  const float* freqs = (const float*)d_in[5];

  char* ws = (char*)d_ws;
  unsigned short* xb   = (unsigned short*)(ws);              // 16 MB, reused as attn_out
  unsigned short* attn = xb;
  unsigned short* wqb  = (unsigned short*)(ws + 16777216);
  unsigned short* wkb  = (unsigned short*)(ws + 25165824);
  unsigned short* wvb  = (unsigned short*)(ws + 27262976);
  unsigned short* wob  = (unsigned short*)(ws + 29360128);
  unsigned short* qlin = (unsigned short*)(ws + 37748736);
  unsigned short* klin = (unsigned short*)(ws + 54525952);
  unsigned short* vlin = (unsigned short*)(ws + 58720256);
  unsigned short* qro  = (unsigned short*)(ws + 62914560);
  unsigned short* kro  = (unsigned short*)(ws + 79691776);
  unsigned short* vt   = (unsigned short*)(ws + 83886080);

  float* out_o = (float*)d_out;
  float* out_k = (float*)d_out + 8388608;
  float* out_v = (float*)d_out + 10485760;

  cvt_kernel<<<4096, 256, 0, stream>>>(x,  xb,  1048576);
  cvt_kernel<<<2048, 256, 0, stream>>>(wq, wqb, 524288);
  cvt_kernel<<<512,  256, 0, stream>>>(wk, wkb, 131072);
  cvt_kernel<<<512,  256, 0, stream>>>(wv, wvb, 131072);
  cvt_kernel<<<2048, 256, 0, stream>>>(wo, wob, 524288);

  gemm_bt<0><<<dim3(16, 32), 256, 0, stream>>>(xb, wqb, qlin, 4096, 2048, 2048);
  gemm_bt<0><<<dim3(4, 32),  256, 0, stream>>>(xb, wkb, klin, 4096, 512, 2048);
  gemm_bt<0><<<dim3(4, 32),  256, 0, stream>>>(xb, wvb, vlin, 4096, 512, 2048);

  rope_kernel<<<20480, 256, 0, stream>>>(qlin, klin, freqs, qro, kro, out_k);
  vtrans_kernel<<<8192, 256, 0, stream>>>(vlin, vt, out_v);

  attn_kernel<<<dim3(32, 16, 2), 256, 0, stream>>>(qro, kro, vt, attn);

  gemm_bt<1><<<dim3(16, 32), 256, 0, stream>>>(attn, wob, out_o, 4096, 2048, 2048);
}

// Round 2
// 512.760 us; speedup vs baseline: 1.7148x; 1.7148x over previous
//
#include <hip/hip_runtime.h>
#include <hip/hip_bf16.h>

#define NH 16
#define NKV 4
#define HD 128
#define ATT_SCALE 0.08838834764831845f

using bf16x8 = __attribute__((ext_vector_type(8))) __bf16;
using f32x4  = __attribute__((ext_vector_type(4))) float;
using u16x8  = __attribute__((ext_vector_type(8))) unsigned short;
using u16x2  = __attribute__((ext_vector_type(2))) unsigned short;

__device__ __forceinline__ unsigned short f2b(float f) {
  __hip_bfloat16 h = __float2bfloat16(f);
  return __builtin_bit_cast(unsigned short, h);
}
__device__ __forceinline__ float b2f(unsigned short u) {
  unsigned int v = ((unsigned int)u) << 16;
  return __builtin_bit_cast(float, v);
}

// ---------------- fp32 -> bf16 conversion (8 elems/thread) ----------------
__global__ __launch_bounds__(256) void cvt_kernel(const float* __restrict__ src,
                                                  unsigned short* __restrict__ dst, int n8) {
  int i = blockIdx.x * 256 + threadIdx.x;
  if (i >= n8) return;
  const float4* s4 = reinterpret_cast<const float4*>(src) + (size_t)i * 2;
  float4 v0 = s4[0], v1 = s4[1];
  u16x8 o;
  o[0] = f2b(v0.x); o[1] = f2b(v0.y); o[2] = f2b(v0.z); o[3] = f2b(v0.w);
  o[4] = f2b(v1.x); o[5] = f2b(v1.y); o[6] = f2b(v1.z); o[7] = f2b(v1.w);
  reinterpret_cast<u16x8*>(dst)[i] = o;
}

// ---------------- GEMM: C[M,N] = A[M,K] * B[N,K]^T  (bf16 in, f32 acc) -----
template<int CF32>
__global__ __launch_bounds__(256) void gemm_bt(const unsigned short* __restrict__ A,
                                               const unsigned short* __restrict__ B,
                                               void* __restrict__ C,
                                               int M, int N, int K) {
  __shared__ unsigned short As[128][40];
  __shared__ unsigned short Bs[128][40];
  const int tid = threadIdx.x;
  const int lane = tid & 63;
  const int wid = tid >> 6;
  const int wm = wid >> 1, wn = wid & 1;
  const int row0 = blockIdx.y * 128, col0 = blockIdx.x * 128;
  const int srow = tid >> 1;
  const int scol = (tid & 1) * 16;
  const unsigned short* Ag = A + (size_t)(row0 + srow) * K + scol;
  const unsigned short* Bg = B + (size_t)(col0 + srow) * K + scol;
  const int fr = lane & 15;
  const int fk = (lane >> 4) * 8;

  f32x4 acc[4][4];
#pragma unroll
  for (int i = 0; i < 4; i++)
#pragma unroll
    for (int j = 0; j < 4; j++) acc[i][j] = f32x4{0.f, 0.f, 0.f, 0.f};

  for (int k0 = 0; k0 < K; k0 += 32) {
    u16x8 a0 = *reinterpret_cast<const u16x8*>(Ag + k0);
    u16x8 a1 = *reinterpret_cast<const u16x8*>(Ag + k0 + 8);
    u16x8 b0 = *reinterpret_cast<const u16x8*>(Bg + k0);
    u16x8 b1 = *reinterpret_cast<const u16x8*>(Bg + k0 + 8);
    __syncthreads();
    *reinterpret_cast<u16x8*>(&As[srow][scol])     = a0;
    *reinterpret_cast<u16x8*>(&As[srow][scol + 8]) = a1;
    *reinterpret_cast<u16x8*>(&Bs[srow][scol])     = b0;
    *reinterpret_cast<u16x8*>(&Bs[srow][scol + 8]) = b1;
    __syncthreads();
    bf16x8 af[4], bfr[4];
#pragma unroll
    for (int i = 0; i < 4; i++)
      af[i] = *reinterpret_cast<const bf16x8*>(&As[wm * 64 + i * 16 + fr][fk]);
#pragma unroll
    for (int i = 0; i < 4; i++)
      bfr[i] = *reinterpret_cast<const bf16x8*>(&Bs[wn * 64 + i * 16 + fr][fk]);
#pragma unroll
    for (int i = 0; i < 4; i++)
#pragma unroll
      for (int j = 0; j < 4; j++)
        acc[i][j] = __builtin_amdgcn_mfma_f32_16x16x32_bf16(af[i], bfr[j], acc[i][j], 0, 0, 0);
  }

  const int r4 = (lane >> 4) * 4;
#pragma unroll
  for (int i = 0; i < 4; i++) {
#pragma unroll
    for (int j = 0; j < 4; j++) {
      int rb = row0 + wm * 64 + i * 16 + r4;
      int cb = col0 + wn * 64 + j * 16 + fr;
#pragma unroll
      for (int r = 0; r < 4; r++) {
        if (CF32)
          reinterpret_cast<float*>(C)[(size_t)(rb + r) * N + cb] = acc[i][j][r];
        else
          reinterpret_cast<unsigned short*>(C)[(size_t)(rb + r) * N + cb] = f2b(acc[i][j][r]);
      }
    }
  }
}

// ---------------- RoPE ----------------------------------------------------
__global__ __launch_bounds__(256) void rope_kernel(const unsigned short* __restrict__ qlin,
                                                   const unsigned short* __restrict__ klin,
                                                   const float* __restrict__ freqs,
                                                   unsigned short* __restrict__ qro,
                                                   unsigned short* __restrict__ kro,
                                                   float* __restrict__ newk) {
  const int NQ = 4096 * 16 * 64;
  const int NK = 4096 * 4 * 64;
  int idx = blockIdx.x * 256 + threadIdx.x;
  if (idx >= NQ + NK) return;
  if (idx < NQ) {
    int i = idx & 63;
    int h = (idx >> 6) & 15;
    int row = idx >> 10;             // b*2048 + s
    int s = row & 2047, b = row >> 11;
    float f = freqs[s * 64 + i];
    float c = cosf(f), sn = sinf(f);
    u16x2 xv = *reinterpret_cast<const u16x2*>(qlin + (size_t)row * 2048 + h * 128 + 2 * i);
    float x1 = b2f(xv.x), x2 = b2f(xv.y);
    float r1 = x1 * c - x2 * sn;
    float r2 = x1 * sn + x2 * c;
    u16x2 o; o.x = f2b(r1); o.y = f2b(r2);
    *reinterpret_cast<u16x2*>(qro + ((size_t)(b * 16 + h) * 2048 + s) * 128 + 2 * i) = o;
  } else {
    idx -= NQ;
    int i = idx & 63;
    int h = (idx >> 6) & 3;
    int row = idx >> 8;
    int s = row & 2047, b = row >> 11;
    float f = freqs[s * 64 + i];
    float c = cosf(f), sn = sinf(f);
    u16x2 xv = *reinterpret_cast<const u16x2*>(klin + (size_t)row * 512 + h * 128 + 2 * i);
    float x1 = b2f(xv.x), x2 = b2f(xv.y);
    float r1 = x1 * c - x2 * sn;
    float r2 = x1 * sn + x2 * c;
    u16x2 o; o.x = f2b(r1); o.y = f2b(r2);
    *reinterpret_cast<u16x2*>(kro + ((size_t)(b * 4 + h) * 2048 + s) * 128 + 2 * i) = o;
    float2 of; of.x = r1; of.y = r2;
    *reinterpret_cast<float2*>(newk + (size_t)row * 512 + h * 128 + 2 * i) = of;
  }
}

// ---------------- V: f32 out + transpose to vt[B][KVH][D][S] with slot perm
// Within each 32-col block, kv stored at slot = g*8 + half*4 + r where
// g=(kv>>2)&3, half=kv>>4, r=kv&3 -> PV B-frag is one contiguous 16B load.
__global__ __launch_bounds__(256) void vtrans_kernel(const unsigned short* __restrict__ vlin,
                                                     unsigned short* __restrict__ vt,
                                                     float* __restrict__ newv) {
  int idx = blockIdx.x * 256 + threadIdx.x;   // 2*2048*512
  if (idx >= 2 * 2048 * 512) return;
  int c = idx & 511, row = idx >> 9;
  int s = row & 2047, b = row >> 11;
  int kvh = c >> 7, d = c & 127;
  unsigned short u = vlin[idx];
  newv[idx] = b2f(u);
  int kl = s & 31;
  int slot = ((kl >> 2) & 3) * 8 + (kl >> 4) * 4 + (kl & 3);
  vt[(size_t)((b * 4 + kvh) * 128 + d) * 2048 + (s & ~31) + slot] = u;
}

// ---------------- flash attention, causal, GQA, swapped-QK ----------------
// grid (16, H, B), 4 independent waves/block; wave handles q-tile pair
// (t, 127-t) sequentially (balanced causal work). KV tile 64. No LDS/barriers.
__global__ __launch_bounds__(256) void attn_kernel(const unsigned short* __restrict__ qro,
                                                   const unsigned short* __restrict__ kro,
                                                   const unsigned short* __restrict__ vt,
                                                   unsigned short* __restrict__ out) {
  const int tid = threadIdx.x, lane = tid & 63, w = tid >> 6;
  const int h = blockIdx.y, b = blockIdx.z;
  const int kvh = h >> 2;
  const int pair = blockIdx.x * 4 + w;          // 0..63
  const int fr = lane & 15, g = lane >> 4, fk = g * 8;
  const unsigned short* Kp = kro + (size_t)(b * 4 + kvh) * 2048 * 128;
  const unsigned short* Vp = vt + (size_t)(b * 4 + kvh) * 128 * 2048;

#pragma unroll 1
  for (int half = 0; half < 2; half++) {
    const int t = half ? (127 - pair) : pair;
    const int qbase = t * 16;
    const unsigned short* Qp = qro + ((size_t)(b * 16 + h) * 2048 + qbase) * 128;
    bf16x8 qf[4];
#pragma unroll
    for (int kk = 0; kk < 4; kk++)
      qf[kk] = *reinterpret_cast<const bf16x8*>(Qp + fr * 128 + kk * 32 + fk);

    f32x4 o[8];
#pragma unroll
    for (int dt = 0; dt < 8; dt++) o[dt] = f32x4{0.f, 0.f, 0.f, 0.f};
    float m = -1e30f, sden = 0.f;                 // state for q = qbase + fr
    const int qrow_s = qbase + fr;
    const int nkv = (qbase + 16 + 63) & ~63;

    for (int kv0 = 0; kv0 < nkv; kv0 += 64) {
      // ---- QK^T swapped: S[kv][q], q = fr, kv = 16*s + 4*g + r ----
      f32x4 sc[4];
      sc[0] = sc[1] = sc[2] = sc[3] = f32x4{0.f, 0.f, 0.f, 0.f};
#pragma unroll
      for (int kk = 0; kk < 4; kk++) {
        bf16x8 ka0 = *reinterpret_cast<const bf16x8*>(Kp + (size_t)(kv0 +  0 + fr) * 128 + kk * 32 + fk);
        bf16x8 ka1 = *reinterpret_cast<const bf16x8*>(Kp + (size_t)(kv0 + 16 + fr) * 128 + kk * 32 + fk);
        bf16x8 ka2 = *reinterpret_cast<const bf16x8*>(Kp + (size_t)(kv0 + 32 + fr) * 128 + kk * 32 + fk);
        bf16x8 ka3 = *reinterpret_cast<const bf16x8*>(Kp + (size_t)(kv0 + 48 + fr) * 128 + kk * 32 + fk);
        sc[0] = __builtin_amdgcn_mfma_f32_16x16x32_bf16(ka0, qf[kk], sc[0], 0, 0, 0);
        sc[1] = __builtin_amdgcn_mfma_f32_16x16x32_bf16(ka1, qf[kk], sc[1], 0, 0, 0);
        sc[2] = __builtin_amdgcn_mfma_f32_16x16x32_bf16(ka2, qf[kk], sc[2], 0, 0, 0);
        sc[3] = __builtin_amdgcn_mfma_f32_16x16x32_bf16(ka3, qf[kk], sc[3], 0, 0, 0);
      }
      // ---- mask + scale + lane-local row max ----
      float mloc = -1e30f;
#pragma unroll
      for (int s = 0; s < 4; s++)
#pragma unroll
        for (int r = 0; r < 4; r++) {
          float v = sc[s][r] * ATT_SCALE;
          if (kv0 + 16 * s + 4 * g + r > qrow_s) v = -1e30f;
          sc[s][r] = v;
          mloc = fmaxf(mloc, v);
        }
      mloc = fmaxf(mloc, __shfl_xor(mloc, 16));
      mloc = fmaxf(mloc, __shfl_xor(mloc, 32));
      float mn = fmaxf(m, mloc);
      float fac = __expf(m - mn);
      m = mn;
      float ps = 0.f;
#pragma unroll
      for (int s = 0; s < 4; s++)
#pragma unroll
        for (int r = 0; r < 4; r++) {
          float e = __expf(sc[s][r] - mn);
          sc[s][r] = e;
          ps += e;
        }
      ps += __shfl_xor(ps, 16);
      ps += __shfl_xor(ps, 32);
      sden = sden * fac + ps;

      // ---- pack P to bf16 A-frags (lane-local, no exchange) ----
      u16x8 pau, pbu;
#pragma unroll
      for (int j = 0; j < 4; j++) {
        pau[j]     = f2b(sc[0][j]);
        pau[4 + j] = f2b(sc[1][j]);
        pbu[j]     = f2b(sc[2][j]);
        pbu[4 + j] = f2b(sc[3][j]);
      }
      bf16x8 pa = __builtin_bit_cast(bf16x8, pau);
      bf16x8 pb = __builtin_bit_cast(bf16x8, pbu);

      // ---- rescale O (O rows: q = g*4 + r; fac lives at lane q) ----
      float facr[4];
#pragma unroll
      for (int r = 0; r < 4; r++) facr[r] = __shfl(fac, g * 4 + r);
#pragma unroll
      for (int dt = 0; dt < 8; dt++) {
        f32x4 t4 = o[dt];
        t4[0] *= facr[0]; t4[1] *= facr[1]; t4[2] *= facr[2]; t4[3] *= facr[3];
        o[dt] = t4;
      }
      // ---- PV: V pre-permuted so B-frag is one 16B load ----
#pragma unroll
      for (int dt = 0; dt < 8; dt++) {
        const unsigned short* vrow = Vp + (size_t)(dt * 16 + fr) * 2048 + kv0;
        bf16x8 v0 = *reinterpret_cast<const bf16x8*>(vrow + fk);
        bf16x8 v1 = *reinterpret_cast<const bf16x8*>(vrow + 32 + fk);
        o[dt] = __builtin_amdgcn_mfma_f32_16x16x32_bf16(pa, v0, o[dt], 0, 0, 0);
        o[dt] = __builtin_amdgcn_mfma_f32_16x16x32_bf16(pb, v1, o[dt], 0, 0, 0);
      }
    }

    // ---- normalize + write (O rows: q = g*4 + r, d = dt*16 + fr) ----
#pragma unroll
    for (int r = 0; r < 4; r++) {
      float inv = 1.0f / __shfl(sden, g * 4 + r);
      int qrow = qbase + g * 4 + r;
      size_t rowoff = ((size_t)b * 2048 + qrow) * 2048 + (size_t)h * 128;
#pragma unroll
      for (int dt = 0; dt < 8; dt++)
        out[rowoff + dt * 16 + fr] = f2b(o[dt][r] * inv);
    }
  }
}

// ---------------- launch ---------------------------------------------------
extern "C" void kernel_launch(void* const* d_in, const int* in_sizes, int n_in,
                              void* d_out, int out_size, void* d_ws, size_t ws_size,
                              hipStream_t stream) {
  const float* x  = (const float*)d_in[0];
  const float* wq = (const float*)d_in[1];
  const float* wk = (const float*)d_in[2];
  const float* wv = (const float*)d_in[3];
  const float* wo = (const float*)d_in[4];
  const float* freqs = (const float*)d_in[5];

  char* ws = (char*)d_ws;
  unsigned short* xb   = (unsigned short*)(ws);              // 16 MB, reused as attn_out
  unsigned short* attn = xb;
  unsigned short* wqb  = (unsigned short*)(ws + 16777216);
  unsigned short* wkb  = (unsigned short*)(ws + 25165824);
  unsigned short* wvb  = (unsigned short*)(ws + 27262976);
  unsigned short* wob  = (unsigned short*)(ws + 29360128);
  unsigned short* qlin = (unsigned short*)(ws + 37748736);
  unsigned short* klin = (unsigned short*)(ws + 54525952);
  unsigned short* vlin = (unsigned short*)(ws + 58720256);
  unsigned short* qro  = (unsigned short*)(ws + 62914560);
  unsigned short* kro  = (unsigned short*)(ws + 79691776);
  unsigned short* vt   = (unsigned short*)(ws + 83886080);

  float* out_o = (float*)d_out;
  float* out_k = (float*)d_out + 8388608;
  float* out_v = (float*)d_out + 10485760;

  cvt_kernel<<<4096, 256, 0, stream>>>(x,  xb,  1048576);
  cvt_kernel<<<2048, 256, 0, stream>>>(wq, wqb, 524288);
  cvt_kernel<<<512,  256, 0, stream>>>(wk, wkb, 131072);
  cvt_kernel<<<512,  256, 0, stream>>>(wv, wvb, 131072);
  cvt_kernel<<<2048, 256, 0, stream>>>(wo, wob, 524288);

  gemm_bt<0><<<dim3(16, 32), 256, 0, stream>>>(xb, wqb, qlin, 4096, 2048, 2048);
  gemm_bt<0><<<dim3(4, 32),  256, 0, stream>>>(xb, wkb, klin, 4096, 512, 2048);
  gemm_bt<0><<<dim3(4, 32),  256, 0, stream>>>(xb, wvb, vlin, 4096, 512, 2048);

  rope_kernel<<<20480, 256, 0, stream>>>(qlin, klin, freqs, qro, kro, out_k);
  vtrans_kernel<<<8192, 256, 0, stream>>>(vlin, vt, out_v);

  attn_kernel<<<dim3(16, 16, 2), 256, 0, stream>>>(qro, kro, vt, attn);

  gemm_bt<1><<<dim3(16, 32), 256, 0, stream>>>(attn, wob, out_o, 4096, 2048, 2048);
}

// Round 3
// 459.547 us; speedup vs baseline: 1.9133x; 1.1158x over previous
//
#include <hip/hip_runtime.h>
#include <hip/hip_bf16.h>

#define NH 16
#define NKV 4
#define HD 128
// ATT_SCALE * log2(e): Q pre-scaled so P = exp2(S_mfma)
#define QSCALE 0.1275174272f

using bf16x8 = __attribute__((ext_vector_type(8))) __bf16;
using f32x4  = __attribute__((ext_vector_type(4))) float;
using u16x8  = __attribute__((ext_vector_type(8))) unsigned short;
using u16x2  = __attribute__((ext_vector_type(2))) unsigned short;

__device__ __forceinline__ unsigned short f2b(float f) {
  __hip_bfloat16 h = __float2bfloat16(f);
  return __builtin_bit_cast(unsigned short, h);
}
__device__ __forceinline__ float b2f(unsigned short u) {
  unsigned int v = ((unsigned int)u) << 16;
  return __builtin_bit_cast(float, v);
}

__device__ __forceinline__ void glds16(const unsigned short* g, unsigned short* l) {
  __builtin_amdgcn_global_load_lds(
      (const __attribute__((address_space(1))) unsigned int*)(const void*)g,
      (__attribute__((address_space(3))) unsigned int*)(void*)l, 16, 0, 0);
}

// ---------------- fp32 -> bf16 conversion (8 elems/thread) ----------------
__global__ __launch_bounds__(256) void cvt_kernel(const float* __restrict__ src,
                                                  unsigned short* __restrict__ dst, int n8) {
  int i = blockIdx.x * 256 + threadIdx.x;
  if (i >= n8) return;
  const float4* s4 = reinterpret_cast<const float4*>(src) + (size_t)i * 2;
  float4 v0 = s4[0], v1 = s4[1];
  u16x8 o;
  o[0] = f2b(v0.x); o[1] = f2b(v0.y); o[2] = f2b(v0.z); o[3] = f2b(v0.w);
  o[4] = f2b(v1.x); o[5] = f2b(v1.y); o[6] = f2b(v1.z); o[7] = f2b(v1.w);
  reinterpret_cast<u16x8*>(dst)[i] = o;
}

// ---------------- GEMM: C[M,N] = A[M,K] * B[N,K]^T, global_load_lds staging
// 128x128 tile, BK=32, 4 waves 2x2, each wave 64x64 (4x4 frags 16x16x32)
template<int CF32>
__global__ __launch_bounds__(256) void gemm_lds(const unsigned short* __restrict__ A,
                                                const unsigned short* __restrict__ B,
                                                void* __restrict__ C,
                                                int M, int N, int K) {
  __shared__ unsigned short As[4096];   // [128][32] linear
  __shared__ unsigned short Bs[4096];
  const int tid = threadIdx.x;
  const int lane = tid & 63;
  const int wid = tid >> 6;
  const int wm = wid >> 1, wn = wid & 1;
  const int row0 = blockIdx.y * 128, col0 = blockIdx.x * 128;
  const int fr = lane & 15;
  const int fk = (lane >> 4) * 8;
  const int srow = tid >> 2;            // 0..63
  const int scol = (tid & 3) * 8;       // element offset
  const unsigned short* Ag = A + (size_t)(row0 + srow) * K + scol;
  const unsigned short* Bg = B + (size_t)(col0 + srow) * K + scol;
  unsigned short* AsW = &As[wid * 512]; // wave-uniform LDS base (bytes w*1024)
  unsigned short* BsW = &Bs[wid * 512];

  f32x4 acc[4][4];
#pragma unroll
  for (int i = 0; i < 4; i++)
#pragma unroll
    for (int j = 0; j < 4; j++) acc[i][j] = f32x4{0.f, 0.f, 0.f, 0.f};

  for (int k0 = 0; k0 < K; k0 += 32) {
    __syncthreads();                    // WAR: prior ds_reads done before overwrite
    glds16(Ag + k0,                 AsW);
    glds16(Ag + k0 + (size_t)64 * K, AsW + 2048);
    glds16(Bg + k0,                 BsW);
    glds16(Bg + k0 + (size_t)64 * K, BsW + 2048);
    __syncthreads();                    // drains vmcnt: tile ready
    bf16x8 af[4], bfr[4];
#pragma unroll
    for (int i = 0; i < 4; i++)
      af[i] = *reinterpret_cast<const bf16x8*>(&As[(wm * 64 + i * 16 + fr) * 32 + fk]);
#pragma unroll
    for (int i = 0; i < 4; i++)
      bfr[i] = *reinterpret_cast<const bf16x8*>(&Bs[(wn * 64 + i * 16 + fr) * 32 + fk]);
#pragma unroll
    for (int i = 0; i < 4; i++)
#pragma unroll
      for (int j = 0; j < 4; j++)
        acc[i][j] = __builtin_amdgcn_mfma_f32_16x16x32_bf16(af[i], bfr[j], acc[i][j], 0, 0, 0);
  }

  const int r4 = (lane >> 4) * 4;
#pragma unroll
  for (int i = 0; i < 4; i++) {
#pragma unroll
    for (int j = 0; j < 4; j++) {
      int rb = row0 + wm * 64 + i * 16 + r4;
      int cb = col0 + wn * 64 + j * 16 + fr;
#pragma unroll
      for (int r = 0; r < 4; r++) {
        if (CF32)
          reinterpret_cast<float*>(C)[(size_t)(rb + r) * N + cb] = acc[i][j][r];
        else
          reinterpret_cast<unsigned short*>(C)[(size_t)(rb + r) * N + cb] = f2b(acc[i][j][r]);
      }
    }
  }
}

// ---------------- RoPE (reads fused qkv [4096][3072]) ---------------------
// qro gets Q pre-scaled by QSCALE; kro + newk unscaled.
__global__ __launch_bounds__(256) void rope_kernel(const unsigned short* __restrict__ qkv,
                                                   const float* __restrict__ freqs,
                                                   unsigned short* __restrict__ qro,
                                                   unsigned short* __restrict__ kro,
                                                   float* __restrict__ newk) {
  const int NQ = 4096 * 16 * 64;
  const int NK = 4096 * 4 * 64;
  int idx = blockIdx.x * 256 + threadIdx.x;
  if (idx >= NQ + NK) return;
  if (idx < NQ) {
    int i = idx & 63;
    int h = (idx >> 6) & 15;
    int row = idx >> 10;             // b*2048 + s
    int s = row & 2047, b = row >> 11;
    float f = freqs[s * 64 + i];
    float c = cosf(f), sn = sinf(f);
    u16x2 xv = *reinterpret_cast<const u16x2*>(qkv + (size_t)row * 3072 + h * 128 + 2 * i);
    float x1 = b2f(xv.x), x2 = b2f(xv.y);
    float r1 = (x1 * c - x2 * sn) * QSCALE;
    float r2 = (x1 * sn + x2 * c) * QSCALE;
    u16x2 o; o.x = f2b(r1); o.y = f2b(r2);
    *reinterpret_cast<u16x2*>(qro + ((size_t)(b * 16 + h) * 2048 + s) * 128 + 2 * i) = o;
  } else {
    idx -= NQ;
    int i = idx & 63;
    int h = (idx >> 6) & 3;
    int row = idx >> 8;
    int s = row & 2047, b = row >> 11;
    float f = freqs[s * 64 + i];
    float c = cosf(f), sn = sinf(f);
    u16x2 xv = *reinterpret_cast<const u16x2*>(qkv + (size_t)row * 3072 + 2048 + h * 128 + 2 * i);
    float x1 = b2f(xv.x), x2 = b2f(xv.y);
    float r1 = x1 * c - x2 * sn;
    float r2 = x1 * sn + x2 * c;
    u16x2 o; o.x = f2b(r1); o.y = f2b(r2);
    *reinterpret_cast<u16x2*>(kro + ((size_t)(b * 4 + h) * 2048 + s) * 128 + 2 * i) = o;
    float2 of; of.x = r1; of.y = r2;
    *reinterpret_cast<float2*>(newk + (size_t)row * 512 + h * 128 + 2 * i) = of;
  }
}

// ---------------- V: f32 out + transpose to vt[B][KVH][D][S] with slot perm
__global__ __launch_bounds__(256) void vtrans_kernel(const unsigned short* __restrict__ qkv,
                                                     unsigned short* __restrict__ vt,
                                                     float* __restrict__ newv) {
  int idx = blockIdx.x * 256 + threadIdx.x;   // 2*2048*512
  if (idx >= 2 * 2048 * 512) return;
  int c = idx & 511, row = idx >> 9;
  int s = row & 2047, b = row >> 11;
  int kvh = c >> 7, d = c & 127;
  unsigned short u = qkv[(size_t)row * 3072 + 2560 + c];
  newv[idx] = b2f(u);
  int kl = s & 31;
  int slot = ((kl >> 2) & 3) * 8 + (kl >> 4) * 4 + (kl & 3);
  vt[(size_t)((b * 4 + kvh) * 128 + d) * 2048 + (s & ~31) + slot] = u;
}

// ---------------- flash attention, causal, GQA, swapped-QK, no-max softmax
// grid (32, 16, 2), 4 waves; wave owns tile t = w*32 + bx (stratified balance).
__global__ __launch_bounds__(256) void attn_kernel(const unsigned short* __restrict__ qro,
                                                   const unsigned short* __restrict__ kro,
                                                   const unsigned short* __restrict__ vt,
                                                   unsigned short* __restrict__ out) {
  const int tid = threadIdx.x, lane = tid & 63, w = tid >> 6;
  const int h = blockIdx.y, b = blockIdx.z;
  const int kvh = h >> 2;
  const int t = w * 32 + blockIdx.x;          // 0..127
  const int qbase = t * 16;
  const int fr = lane & 15, g = lane >> 4, fk = g * 8;
  const unsigned short* Kp = kro + (size_t)(b * 4 + kvh) * 2048 * 128;
  const unsigned short* Vp = vt + (size_t)(b * 4 + kvh) * 128 * 2048;
  const unsigned short* Qp = qro + ((size_t)(b * 16 + h) * 2048 + qbase) * 128;

  bf16x8 qf[4];
#pragma unroll
  for (int kk = 0; kk < 4; kk++)
    qf[kk] = *reinterpret_cast<const bf16x8*>(Qp + fr * 128 + kk * 32 + fk);

  u16x8 onesu;
#pragma unroll
  for (int j = 0; j < 8; j++) onesu[j] = 0x3F80;  // bf16 1.0
  bf16x8 ones = __builtin_bit_cast(bf16x8, onesu);

  f32x4 o[8];
#pragma unroll
  for (int dt = 0; dt < 8; dt++) o[dt] = f32x4{0.f, 0.f, 0.f, 0.f};
  f32x4 dacc = f32x4{0.f, 0.f, 0.f, 0.f};
  const int qrow_s = qbase + fr;
  const int nfull = (qbase >= 63) ? ((qbase - 63) >> 6) + 1 : 0;

  auto step = [&](int kv0, bool mask) {
    f32x4 sc[4];
    sc[0] = sc[1] = sc[2] = sc[3] = f32x4{0.f, 0.f, 0.f, 0.f};
#pragma unroll
    for (int kk = 0; kk < 4; kk++) {
      const unsigned short* kbase = Kp + (size_t)(kv0 + fr) * 128 + kk * 32 + fk;
      bf16x8 ka0 = *reinterpret_cast<const bf16x8*>(kbase);
      bf16x8 ka1 = *reinterpret_cast<const bf16x8*>(kbase + 16 * 128);
      bf16x8 ka2 = *reinterpret_cast<const bf16x8*>(kbase + 32 * 128);
      bf16x8 ka3 = *reinterpret_cast<const bf16x8*>(kbase + 48 * 128);
      sc[0] = __builtin_amdgcn_mfma_f32_16x16x32_bf16(ka0, qf[kk], sc[0], 0, 0, 0);
      sc[1] = __builtin_amdgcn_mfma_f32_16x16x32_bf16(ka1, qf[kk], sc[1], 0, 0, 0);
      sc[2] = __builtin_amdgcn_mfma_f32_16x16x32_bf16(ka2, qf[kk], sc[2], 0, 0, 0);
      sc[3] = __builtin_amdgcn_mfma_f32_16x16x32_bf16(ka3, qf[kk], sc[3], 0, 0, 0);
    }
    // P = exp2(S) (Q pre-scaled); mask only on boundary tile
#pragma unroll
    for (int s = 0; s < 4; s++)
#pragma unroll
      for (int r = 0; r < 4; r++) {
        float v = sc[s][r];
        if (mask && (kv0 + 16 * s + 4 * g + r > qrow_s)) v = -1e30f;
        sc[s][r] = __builtin_amdgcn_exp2f(v);
      }
    u16x8 pau, pbu;
#pragma unroll
    for (int j = 0; j < 4; j++) {
      pau[j]     = f2b(sc[0][j]);
      pau[4 + j] = f2b(sc[1][j]);
      pbu[j]     = f2b(sc[2][j]);
      pbu[4 + j] = f2b(sc[3][j]);
    }
    bf16x8 pa = __builtin_bit_cast(bf16x8, pau);
    bf16x8 pb = __builtin_bit_cast(bf16x8, pbu);
    // denominator: row-sum via ones-MFMA (lands in O's C/D layout)
    dacc = __builtin_amdgcn_mfma_f32_16x16x32_bf16(pa, ones, dacc, 0, 0, 0);
    dacc = __builtin_amdgcn_mfma_f32_16x16x32_bf16(pb, ones, dacc, 0, 0, 0);
#pragma unroll
    for (int dt = 0; dt < 8; dt++) {
      const unsigned short* vrow = Vp + (size_t)(dt * 16 + fr) * 2048 + kv0;
      bf16x8 v0 = *reinterpret_cast<const bf16x8*>(vrow + fk);
      bf16x8 v1 = *reinterpret_cast<const bf16x8*>(vrow + 32 + fk);
      o[dt] = __builtin_amdgcn_mfma_f32_16x16x32_bf16(pa, v0, o[dt], 0, 0, 0);
      o[dt] = __builtin_amdgcn_mfma_f32_16x16x32_bf16(pb, v1, o[dt], 0, 0, 0);
    }
  };

  for (int i = 0; i < nfull; i++) step(i * 64, false);
  step(nfull * 64, true);     // exactly one boundary tile per q-tile

#pragma unroll
  for (int r = 0; r < 4; r++) {
    float inv = 1.0f / dacc[r];
    int qrow = qbase + g * 4 + r;
    size_t rowoff = ((size_t)b * 2048 + qrow) * 2048 + (size_t)h * 128;
#pragma unroll
    for (int dt = 0; dt < 8; dt++)
      out[rowoff + dt * 16 + fr] = f2b(o[dt][r] * inv);
  }
}

// ---------------- launch ---------------------------------------------------
extern "C" void kernel_launch(void* const* d_in, const int* in_sizes, int n_in,
                              void* d_out, int out_size, void* d_ws, size_t ws_size,
                              hipStream_t stream) {
  const float* x  = (const float*)d_in[0];
  const float* wq = (const float*)d_in[1];
  const float* wk = (const float*)d_in[2];
  const float* wv = (const float*)d_in[3];
  const float* wo = (const float*)d_in[4];
  const float* freqs = (const float*)d_in[5];

  char* ws = (char*)d_ws;
  unsigned short* xb    = (unsigned short*)(ws);             // 16 MB, reused as attn out
  unsigned short* attn  = xb;
  unsigned short* wqkvb = (unsigned short*)(ws + 16777216);  // [3072][2048] bf16, 12 MB
  unsigned short* wob   = (unsigned short*)(ws + 29360128);  // 8 MB
  unsigned short* qkv   = (unsigned short*)(ws + 37748736);  // [4096][3072] bf16, 24 MB
  unsigned short* qro   = (unsigned short*)(ws + 62914560);  // 16 MB
  unsigned short* kro   = (unsigned short*)(ws + 79691776);  // 4 MB
  unsigned short* vt    = (unsigned short*)(ws + 83886080);  // 4 MB

  float* out_o = (float*)d_out;
  float* out_k = (float*)d_out + 8388608;
  float* out_v = (float*)d_out + 10485760;

  cvt_kernel<<<4096, 256, 0, stream>>>(x,  xb, 1048576);
  cvt_kernel<<<2048, 256, 0, stream>>>(wq, wqkvb,           524288);
  cvt_kernel<<<512,  256, 0, stream>>>(wk, wqkvb + 4194304, 131072);
  cvt_kernel<<<512,  256, 0, stream>>>(wv, wqkvb + 5242880, 131072);
  cvt_kernel<<<2048, 256, 0, stream>>>(wo, wob, 524288);

  gemm_lds<0><<<dim3(24, 32), 256, 0, stream>>>(xb, wqkvb, qkv, 4096, 3072, 2048);

  rope_kernel<<<20480, 256, 0, stream>>>(qkv, freqs, qro, kro, out_k);
  vtrans_kernel<<<8192, 256, 0, stream>>>(qkv, vt, out_v);

  attn_kernel<<<dim3(32, 16, 2), 256, 0, stream>>>(qro, kro, vt, attn);

  gemm_lds<1><<<dim3(16, 32), 256, 0, stream>>>(attn, wob, out_o, 4096, 2048, 2048);
}

// Round 4
// 252.061 us; speedup vs baseline: 3.4883x; 1.8232x over previous
//
#include <hip/hip_runtime.h>
#include <hip/hip_bf16.h>

#define NH 16
#define NKV 4
#define HD 128
// ATT_SCALE * log2(e): Q pre-scaled so P = exp2(S_mfma)
#define QSCALE 0.1275174272f

using bf16x8 = __attribute__((ext_vector_type(8))) __bf16;
using f32x4  = __attribute__((ext_vector_type(4))) float;
using u16x8  = __attribute__((ext_vector_type(8))) unsigned short;
using u16x2  = __attribute__((ext_vector_type(2))) unsigned short;

__device__ __forceinline__ unsigned short f2b(float f) {
  __hip_bfloat16 h = __float2bfloat16(f);
  return __builtin_bit_cast(unsigned short, h);
}
__device__ __forceinline__ float b2f(unsigned short u) {
  unsigned int v = ((unsigned int)u) << 16;
  return __builtin_bit_cast(float, v);
}

__device__ __forceinline__ void glds16(const unsigned short* g, unsigned short* l) {
  __builtin_amdgcn_global_load_lds(
      (const __attribute__((address_space(1))) unsigned int*)(const void*)g,
      (__attribute__((address_space(3))) unsigned int*)(void*)l, 16, 0, 0);
}

// ---------------- fp32 -> bf16 conversion (8 elems/thread) ----------------
__global__ __launch_bounds__(256) void cvt_kernel(const float* __restrict__ src,
                                                  unsigned short* __restrict__ dst, int n8) {
  int i = blockIdx.x * 256 + threadIdx.x;
  if (i >= n8) return;
  const float4* s4 = reinterpret_cast<const float4*>(src) + (size_t)i * 2;
  float4 v0 = s4[0], v1 = s4[1];
  u16x8 o;
  o[0] = f2b(v0.x); o[1] = f2b(v0.y); o[2] = f2b(v0.z); o[3] = f2b(v0.w);
  o[4] = f2b(v1.x); o[5] = f2b(v1.y); o[6] = f2b(v1.z); o[7] = f2b(v1.w);
  reinterpret_cast<u16x8*>(dst)[i] = o;
}

// ---------------- GEMM: C[M,N] = A[M,K] * B[N,K]^T, global_load_lds staging
template<int CF32>
__global__ __launch_bounds__(256) void gemm_lds(const unsigned short* __restrict__ A,
                                                const unsigned short* __restrict__ B,
                                                void* __restrict__ C,
                                                int M, int N, int K) {
  __shared__ unsigned short As[4096];   // [128][32] linear
  __shared__ unsigned short Bs[4096];
  const int tid = threadIdx.x;
  const int lane = tid & 63;
  const int wid = tid >> 6;
  const int wm = wid >> 1, wn = wid & 1;
  const int row0 = blockIdx.y * 128, col0 = blockIdx.x * 128;
  const int fr = lane & 15;
  const int fk = (lane >> 4) * 8;
  const int srow = tid >> 2;            // 0..63
  const int scol = (tid & 3) * 8;       // element offset
  const unsigned short* Ag = A + (size_t)(row0 + srow) * K + scol;
  const unsigned short* Bg = B + (size_t)(col0 + srow) * K + scol;
  unsigned short* AsW = &As[wid * 512];
  unsigned short* BsW = &Bs[wid * 512];

  f32x4 acc[4][4];
#pragma unroll
  for (int i = 0; i < 4; i++)
#pragma unroll
    for (int j = 0; j < 4; j++) acc[i][j] = f32x4{0.f, 0.f, 0.f, 0.f};

  for (int k0 = 0; k0 < K; k0 += 32) {
    __syncthreads();
    glds16(Ag + k0,                  AsW);
    glds16(Ag + k0 + (size_t)64 * K, AsW + 2048);
    glds16(Bg + k0,                  BsW);
    glds16(Bg + k0 + (size_t)64 * K, BsW + 2048);
    __syncthreads();
    bf16x8 af[4], bfr[4];
#pragma unroll
    for (int i = 0; i < 4; i++)
      af[i] = *reinterpret_cast<const bf16x8*>(&As[(wm * 64 + i * 16 + fr) * 32 + fk]);
#pragma unroll
    for (int i = 0; i < 4; i++)
      bfr[i] = *reinterpret_cast<const bf16x8*>(&Bs[(wn * 64 + i * 16 + fr) * 32 + fk]);
#pragma unroll
    for (int i = 0; i < 4; i++)
#pragma unroll
      for (int j = 0; j < 4; j++)
        acc[i][j] = __builtin_amdgcn_mfma_f32_16x16x32_bf16(af[i], bfr[j], acc[i][j], 0, 0, 0);
  }

  const int r4 = (lane >> 4) * 4;
#pragma unroll
  for (int i = 0; i < 4; i++) {
#pragma unroll
    for (int j = 0; j < 4; j++) {
      int rb = row0 + wm * 64 + i * 16 + r4;
      int cb = col0 + wn * 64 + j * 16 + fr;
#pragma unroll
      for (int r = 0; r < 4; r++) {
        if (CF32)
          reinterpret_cast<float*>(C)[(size_t)(rb + r) * N + cb] = acc[i][j][r];
        else
          reinterpret_cast<unsigned short*>(C)[(size_t)(rb + r) * N + cb] = f2b(acc[i][j][r]);
      }
    }
  }
}

// ---------------- RoPE (reads fused qkv [4096][3072]) ---------------------
__global__ __launch_bounds__(256) void rope_kernel(const unsigned short* __restrict__ qkv,
                                                   const float* __restrict__ freqs,
                                                   unsigned short* __restrict__ qro,
                                                   unsigned short* __restrict__ kro,
                                                   float* __restrict__ newk) {
  const int NQ = 4096 * 16 * 64;
  const int NK = 4096 * 4 * 64;
  int idx = blockIdx.x * 256 + threadIdx.x;
  if (idx >= NQ + NK) return;
  if (idx < NQ) {
    int i = idx & 63;
    int h = (idx >> 6) & 15;
    int row = idx >> 10;             // b*2048 + s
    int s = row & 2047, b = row >> 11;
    float f = freqs[s * 64 + i];
    float c = cosf(f), sn = sinf(f);
    u16x2 xv = *reinterpret_cast<const u16x2*>(qkv + (size_t)row * 3072 + h * 128 + 2 * i);
    float x1 = b2f(xv.x), x2 = b2f(xv.y);
    float r1 = (x1 * c - x2 * sn) * QSCALE;
    float r2 = (x1 * sn + x2 * c) * QSCALE;
    u16x2 o; o.x = f2b(r1); o.y = f2b(r2);
    *reinterpret_cast<u16x2*>(qro + ((size_t)(b * 16 + h) * 2048 + s) * 128 + 2 * i) = o;
  } else {
    idx -= NQ;
    int i = idx & 63;
    int h = (idx >> 6) & 3;
    int row = idx >> 8;
    int s = row & 2047, b = row >> 11;
    float f = freqs[s * 64 + i];
    float c = cosf(f), sn = sinf(f);
    u16x2 xv = *reinterpret_cast<const u16x2*>(qkv + (size_t)row * 3072 + 2048 + h * 128 + 2 * i);
    float x1 = b2f(xv.x), x2 = b2f(xv.y);
    float r1 = x1 * c - x2 * sn;
    float r2 = x1 * sn + x2 * c;
    u16x2 o; o.x = f2b(r1); o.y = f2b(r2);
    *reinterpret_cast<u16x2*>(kro + ((size_t)(b * 4 + h) * 2048 + s) * 128 + 2 * i) = o;
    float2 of; of.x = r1; of.y = r2;
    *reinterpret_cast<float2*>(newk + (size_t)row * 512 + h * 128 + 2 * i) = of;
  }
}

// ---------------- V: f32 out + transpose to vt[B][KVH][D][S] with slot perm
__global__ __launch_bounds__(256) void vtrans_kernel(const unsigned short* __restrict__ qkv,
                                                     unsigned short* __restrict__ vt,
                                                     float* __restrict__ newv) {
  int idx = blockIdx.x * 256 + threadIdx.x;   // 2*2048*512
  if (idx >= 2 * 2048 * 512) return;
  int c = idx & 511, row = idx >> 9;
  int s = row & 2047, b = row >> 11;
  int kvh = c >> 7, d = c & 127;
  unsigned short u = qkv[(size_t)row * 3072 + 2560 + c];
  newv[idx] = b2f(u);
  int kl = s & 31;
  int slot = ((kl >> 2) & 3) * 8 + (kl >> 4) * 4 + (kl & 3);
  vt[(size_t)((b * 4 + kvh) * 128 + d) * 2048 + (s & ~31) + slot] = u;
}

// ---------------- flash attention: block = (q-tile, kvh, b), 4 waves = 4 q-heads
// K/V LDS-staged (global_load_lds, XOR-swizzled src), double-buffered.
__global__ __launch_bounds__(256) void attn_kernel(const unsigned short* __restrict__ qro,
                                                   const unsigned short* __restrict__ kro,
                                                   const unsigned short* __restrict__ vt,
                                                   unsigned short* __restrict__ out) {
  __shared__ unsigned short Ks[2][64 * 128];   // [kv][d], rows 256B, swizzled
  __shared__ unsigned short Vs[2][128 * 64];   // [d][kv-slot], rows 128B, swizzled
  const int tid = threadIdx.x, lane = tid & 63, w = tid >> 6;
  const int kvh = blockIdx.y, b = blockIdx.z;
  const int h = kvh * 4 + w;                   // each wave = one q-head
  const int t = 127 - blockIdx.x;              // heavy blocks first
  const int qbase = t * 16;
  const int fr = lane & 15, g = lane >> 4, fk = g * 8;
  const unsigned short* Kp = kro + (size_t)(b * 4 + kvh) * 2048 * 128;
  const unsigned short* Vtp = vt + (size_t)(b * 4 + kvh) * 128 * 2048;
  const unsigned short* Qp = qro + ((size_t)(b * 16 + h) * 2048 + qbase) * 128;

  bf16x8 qf[4];
#pragma unroll
  for (int kk = 0; kk < 4; kk++)
    qf[kk] = *reinterpret_cast<const bf16x8*>(Qp + fr * 128 + kk * 32 + fk);

  u16x8 onesu;
#pragma unroll
  for (int j = 0; j < 8; j++) onesu[j] = 0x3F80;  // bf16 1.0
  bf16x8 ones = __builtin_bit_cast(bf16x8, onesu);

  f32x4 o[8];
#pragma unroll
  for (int dt = 0; dt < 8; dt++) o[dt] = f32x4{0.f, 0.f, 0.f, 0.f};
  f32x4 dacc = f32x4{0.f, 0.f, 0.f, 0.f};
  const int qrow_s = qbase + fr;
  const int nfull = (qbase >= 63) ? ((qbase - 63) >> 6) + 1 : 0;
  const int niter = nfull + 1;

  const int krow = w * 16 + (lane >> 4);       // stage dest rows (K)
  const int kcol = lane & 15;
  const int vrow_s = w * 32 + (lane >> 3);     // stage dest rows (V)
  const int vcol = lane & 7;

  auto stage = [&](int kv0, int buf) {
    unsigned short* Kb = &Ks[buf][0];
    unsigned short* Vb = &Vs[buf][0];
#pragma unroll
    for (int j = 0; j < 4; j++) {
      int r = krow + j * 4;
      glds16(Kp + (size_t)(kv0 + r) * 128 + ((kcol ^ (r & 7)) * 8),
             Kb + (w * 16 + j * 4) * 128);
    }
#pragma unroll
    for (int j = 0; j < 4; j++) {
      int r = vrow_s + j * 8;
      glds16(Vtp + (size_t)r * 2048 + kv0 + ((vcol ^ (r & 7)) * 8),
             Vb + (w * 32 + j * 8) * 64);
    }
  };

  auto step = [&](int kv0, bool mask, int buf) {
    const unsigned short* Kb = &Ks[buf][0];
    const unsigned short* Vb = &Vs[buf][0];
    f32x4 sc[4];
    sc[0] = sc[1] = sc[2] = sc[3] = f32x4{0.f, 0.f, 0.f, 0.f};
#pragma unroll
    for (int kk = 0; kk < 4; kk++) {
      int blk = ((kk * 4 + g) ^ (fr & 7)) * 8;
      bf16x8 ka0 = *reinterpret_cast<const bf16x8*>(Kb + (fr +  0) * 128 + blk);
      bf16x8 ka1 = *reinterpret_cast<const bf16x8*>(Kb + (fr + 16) * 128 + blk);
      bf16x8 ka2 = *reinterpret_cast<const bf16x8*>(Kb + (fr + 32) * 128 + blk);
      bf16x8 ka3 = *reinterpret_cast<const bf16x8*>(Kb + (fr + 48) * 128 + blk);
      sc[0] = __builtin_amdgcn_mfma_f32_16x16x32_bf16(ka0, qf[kk], sc[0], 0, 0, 0);
      sc[1] = __builtin_amdgcn_mfma_f32_16x16x32_bf16(ka1, qf[kk], sc[1], 0, 0, 0);
      sc[2] = __builtin_amdgcn_mfma_f32_16x16x32_bf16(ka2, qf[kk], sc[2], 0, 0, 0);
      sc[3] = __builtin_amdgcn_mfma_f32_16x16x32_bf16(ka3, qf[kk], sc[3], 0, 0, 0);
    }
#pragma unroll
    for (int s = 0; s < 4; s++)
#pragma unroll
      for (int r = 0; r < 4; r++) {
        float v = sc[s][r];
        if (mask && (kv0 + 16 * s + 4 * g + r > qrow_s)) v = -1e30f;
        sc[s][r] = __builtin_amdgcn_exp2f(v);
      }
    u16x8 pau, pbu;
#pragma unroll
    for (int j = 0; j < 4; j++) {
      pau[j]     = f2b(sc[0][j]);
      pau[4 + j] = f2b(sc[1][j]);
      pbu[j]     = f2b(sc[2][j]);
      pbu[4 + j] = f2b(sc[3][j]);
    }
    bf16x8 pa = __builtin_bit_cast(bf16x8, pau);
    bf16x8 pb = __builtin_bit_cast(bf16x8, pbu);
    dacc = __builtin_amdgcn_mfma_f32_16x16x32_bf16(pa, ones, dacc, 0, 0, 0);
    dacc = __builtin_amdgcn_mfma_f32_16x16x32_bf16(pb, ones, dacc, 0, 0, 0);
#pragma unroll
    for (int dt = 0; dt < 8; dt++) {
      const unsigned short* vr = Vb + (dt * 16 + fr) * 64;
      bf16x8 v0 = *reinterpret_cast<const bf16x8*>(vr + ((g       ^ (fr & 7)) * 8));
      bf16x8 v1 = *reinterpret_cast<const bf16x8*>(vr + (((4 + g) ^ (fr & 7)) * 8));
      o[dt] = __builtin_amdgcn_mfma_f32_16x16x32_bf16(pa, v0, o[dt], 0, 0, 0);
      o[dt] = __builtin_amdgcn_mfma_f32_16x16x32_bf16(pb, v1, o[dt], 0, 0, 0);
    }
  };

  stage(0, 0);
  int buf = 0;
  for (int i = 0; i < niter; i++) {
    __syncthreads();                 // tile i ready; prev compute done
    if (i + 1 < niter) stage((i + 1) * 64, buf ^ 1);
    step(i * 64, i == nfull, buf);
    buf ^= 1;
  }

#pragma unroll
  for (int r = 0; r < 4; r++) {
    float inv = 1.0f / dacc[r];
    int qrow = qbase + g * 4 + r;
    size_t rowoff = ((size_t)b * 2048 + qrow) * 2048 + (size_t)h * 128;
#pragma unroll
    for (int dt = 0; dt < 8; dt++)
      out[rowoff + dt * 16 + fr] = f2b(o[dt][r] * inv);
  }
}

// ---------------- launch ---------------------------------------------------
extern "C" void kernel_launch(void* const* d_in, const int* in_sizes, int n_in,
                              void* d_out, int out_size, void* d_ws, size_t ws_size,
                              hipStream_t stream) {
  const float* x  = (const float*)d_in[0];
  const float* wq = (const float*)d_in[1];
  const float* wk = (const float*)d_in[2];
  const float* wv = (const float*)d_in[3];
  const float* wo = (const float*)d_in[4];
  const float* freqs = (const float*)d_in[5];

  char* ws = (char*)d_ws;
  unsigned short* xb    = (unsigned short*)(ws);             // 16 MB, reused as attn out
  unsigned short* attn  = xb;
  unsigned short* wqkvb = (unsigned short*)(ws + 16777216);  // [3072][2048] bf16
  unsigned short* wob   = (unsigned short*)(ws + 29360128);
  unsigned short* qkv   = (unsigned short*)(ws + 37748736);  // [4096][3072] bf16
  unsigned short* qro   = (unsigned short*)(ws + 62914560);
  unsigned short* kro   = (unsigned short*)(ws + 79691776);
  unsigned short* vt    = (unsigned short*)(ws + 83886080);

  float* out_o = (float*)d_out;
  float* out_k = (float*)d_out + 8388608;
  float* out_v = (float*)d_out + 10485760;

  cvt_kernel<<<4096, 256, 0, stream>>>(x,  xb, 1048576);
  cvt_kernel<<<2048, 256, 0, stream>>>(wq, wqkvb,           524288);
  cvt_kernel<<<512,  256, 0, stream>>>(wk, wqkvb + 4194304, 131072);
  cvt_kernel<<<512,  256, 0, stream>>>(wv, wqkvb + 5242880, 131072);
  cvt_kernel<<<2048, 256, 0, stream>>>(wo, wob, 524288);

  gemm_lds<0><<<dim3(24, 32), 256, 0, stream>>>(xb, wqkvb, qkv, 4096, 3072, 2048);

  rope_kernel<<<20480, 256, 0, stream>>>(qkv, freqs, qro, kro, out_k);
  vtrans_kernel<<<8192, 256, 0, stream>>>(qkv, vt, out_v);

  attn_kernel<<<dim3(128, 4, 2), 256, 0, stream>>>(qro, kro, vt, attn);

  gemm_lds<1><<<dim3(16, 32), 256, 0, stream>>>(attn, wob, out_o, 4096, 2048, 2048);
}

// Round 5
// 224.494 us; speedup vs baseline: 3.9167x; 1.1228x over previous
//
#include <hip/hip_runtime.h>
#include <hip/hip_bf16.h>

#define NH 16
#define NKV 4
#define HD 128
// ATT_SCALE * log2(e): Q pre-scaled so P = exp2(S_mfma)
#define QSCALE 0.1275174272f

using bf16x8 = __attribute__((ext_vector_type(8))) __bf16;
using f32x4  = __attribute__((ext_vector_type(4))) float;
using u16x8  = __attribute__((ext_vector_type(8))) unsigned short;
using u16x2  = __attribute__((ext_vector_type(2))) unsigned short;

__device__ __forceinline__ unsigned short f2b(float f) {
  __hip_bfloat16 h = __float2bfloat16(f);
  return __builtin_bit_cast(unsigned short, h);
}
__device__ __forceinline__ float b2f(unsigned short u) {
  unsigned int v = ((unsigned int)u) << 16;
  return __builtin_bit_cast(float, v);
}

__device__ __forceinline__ void glds16(const unsigned short* g, unsigned short* l) {
  __builtin_amdgcn_global_load_lds(
      (const __attribute__((address_space(1))) unsigned int*)(const void*)g,
      (__attribute__((address_space(3))) unsigned int*)(void*)l, 16, 0, 0);
}

// ---------------- fused fp32 -> bf16 conversion (8 elems/thread) ----------
// ranges: x | wq | wk | wv | wo  (wq/wk/wv -> contiguous wqkvb)
__global__ __launch_bounds__(256) void cvt_fused(const float* __restrict__ x,
                                                 const float* __restrict__ wq,
                                                 const float* __restrict__ wk,
                                                 const float* __restrict__ wv,
                                                 const float* __restrict__ wo,
                                                 unsigned short* __restrict__ xb,
                                                 unsigned short* __restrict__ wqkvb,
                                                 unsigned short* __restrict__ wob) {
  int i = blockIdx.x * 256 + threadIdx.x;
  const float* src;
  unsigned short* dst;
  int off;
  if (i < 1048576)      { src = x;  dst = xb;              off = i; }
  else if (i < 1572864) { src = wq; dst = wqkvb;           off = i - 1048576; }
  else if (i < 1703936) { src = wk; dst = wqkvb + 4194304; off = i - 1572864; }
  else if (i < 1835008) { src = wv; dst = wqkvb + 5242880; off = i - 1703936; }
  else                  { src = wo; dst = wob;             off = i - 1835008; }
  const float4* s4 = reinterpret_cast<const float4*>(src) + (size_t)off * 2;
  float4 v0 = s4[0], v1 = s4[1];
  u16x8 o;
  o[0] = f2b(v0.x); o[1] = f2b(v0.y); o[2] = f2b(v0.z); o[3] = f2b(v0.w);
  o[4] = f2b(v1.x); o[5] = f2b(v1.y); o[6] = f2b(v1.z); o[7] = f2b(v1.w);
  reinterpret_cast<u16x8*>(dst)[off] = o;
}

// ---------------- GEMM: C[M,N] = A[M,K] * B[N,K]^T, global_load_lds staging
template<int CF32>
__global__ __launch_bounds__(256) void gemm_lds(const unsigned short* __restrict__ A,
                                                const unsigned short* __restrict__ B,
                                                void* __restrict__ C,
                                                int M, int N, int K) {
  __shared__ unsigned short As[4096];   // [128][32] linear
  __shared__ unsigned short Bs[4096];
  const int tid = threadIdx.x;
  const int lane = tid & 63;
  const int wid = tid >> 6;
  const int wm = wid >> 1, wn = wid & 1;
  const int row0 = blockIdx.y * 128, col0 = blockIdx.x * 128;
  const int fr = lane & 15;
  const int fk = (lane >> 4) * 8;
  const int srow = tid >> 2;            // 0..63
  const int scol = (tid & 3) * 8;       // element offset
  const unsigned short* Ag = A + (size_t)(row0 + srow) * K + scol;
  const unsigned short* Bg = B + (size_t)(col0 + srow) * K + scol;
  unsigned short* AsW = &As[wid * 512];
  unsigned short* BsW = &Bs[wid * 512];

  f32x4 acc[4][4];
#pragma unroll
  for (int i = 0; i < 4; i++)
#pragma unroll
    for (int j = 0; j < 4; j++) acc[i][j] = f32x4{0.f, 0.f, 0.f, 0.f};

  for (int k0 = 0; k0 < K; k0 += 32) {
    __syncthreads();
    glds16(Ag + k0,                  AsW);
    glds16(Ag + k0 + (size_t)64 * K, AsW + 2048);
    glds16(Bg + k0,                  BsW);
    glds16(Bg + k0 + (size_t)64 * K, BsW + 2048);
    __syncthreads();
    bf16x8 af[4], bfr[4];
#pragma unroll
    for (int i = 0; i < 4; i++)
      af[i] = *reinterpret_cast<const bf16x8*>(&As[(wm * 64 + i * 16 + fr) * 32 + fk]);
#pragma unroll
    for (int i = 0; i < 4; i++)
      bfr[i] = *reinterpret_cast<const bf16x8*>(&Bs[(wn * 64 + i * 16 + fr) * 32 + fk]);
#pragma unroll
    for (int i = 0; i < 4; i++)
#pragma unroll
      for (int j = 0; j < 4; j++)
        acc[i][j] = __builtin_amdgcn_mfma_f32_16x16x32_bf16(af[i], bfr[j], acc[i][j], 0, 0, 0);
  }

  const int r4 = (lane >> 4) * 4;
#pragma unroll
  for (int i = 0; i < 4; i++) {
#pragma unroll
    for (int j = 0; j < 4; j++) {
      int rb = row0 + wm * 64 + i * 16 + r4;
      int cb = col0 + wn * 64 + j * 16 + fr;
#pragma unroll
      for (int r = 0; r < 4; r++) {
        if (CF32)
          reinterpret_cast<float*>(C)[(size_t)(rb + r) * N + cb] = acc[i][j][r];
        else
          reinterpret_cast<unsigned short*>(C)[(size_t)(rb + r) * N + cb] = f2b(acc[i][j][r]);
      }
    }
  }
}

// ---------------- RoPE (reads fused qkv [4096][3072]) ---------------------
__global__ __launch_bounds__(256) void rope_kernel(const unsigned short* __restrict__ qkv,
                                                   const float* __restrict__ freqs,
                                                   unsigned short* __restrict__ qro,
                                                   unsigned short* __restrict__ kro,
                                                   float* __restrict__ newk) {
  const int NQ = 4096 * 16 * 64;
  const int NK = 4096 * 4 * 64;
  int idx = blockIdx.x * 256 + threadIdx.x;
  if (idx >= NQ + NK) return;
  if (idx < NQ) {
    int i = idx & 63;
    int h = (idx >> 6) & 15;
    int row = idx >> 10;             // b*2048 + s
    int s = row & 2047, b = row >> 11;
    float f = freqs[s * 64 + i];
    float c = cosf(f), sn = sinf(f);
    u16x2 xv = *reinterpret_cast<const u16x2*>(qkv + (size_t)row * 3072 + h * 128 + 2 * i);
    float x1 = b2f(xv.x), x2 = b2f(xv.y);
    float r1 = (x1 * c - x2 * sn) * QSCALE;
    float r2 = (x1 * sn + x2 * c) * QSCALE;
    u16x2 o; o.x = f2b(r1); o.y = f2b(r2);
    *reinterpret_cast<u16x2*>(qro + ((size_t)(b * 16 + h) * 2048 + s) * 128 + 2 * i) = o;
  } else {
    idx -= NQ;
    int i = idx & 63;
    int h = (idx >> 6) & 3;
    int row = idx >> 8;
    int s = row & 2047, b = row >> 11;
    float f = freqs[s * 64 + i];
    float c = cosf(f), sn = sinf(f);
    u16x2 xv = *reinterpret_cast<const u16x2*>(qkv + (size_t)row * 3072 + 2048 + h * 128 + 2 * i);
    float x1 = b2f(xv.x), x2 = b2f(xv.y);
    float r1 = x1 * c - x2 * sn;
    float r2 = x1 * sn + x2 * c;
    u16x2 o; o.x = f2b(r1); o.y = f2b(r2);
    *reinterpret_cast<u16x2*>(kro + ((size_t)(b * 4 + h) * 2048 + s) * 128 + 2 * i) = o;
    float2 of; of.x = r1; of.y = r2;
    *reinterpret_cast<float2*>(newk + (size_t)row * 512 + h * 128 + 2 * i) = of;
  }
}

// ---------------- V: LDS-tiled transpose -> vt[B][KVH][D][S] (slot-permuted)
// + coalesced newv f32 copy. Block = 32 s-rows x 128 d for one (b,kvh).
__global__ __launch_bounds__(256) void vtrans_kernel(const unsigned short* __restrict__ qkv,
                                                     unsigned short* __restrict__ vt,
                                                     float* __restrict__ newv) {
  __shared__ unsigned short T[32][136];
  const int st = blockIdx.x;           // 0..63
  const int kvh = blockIdx.y & 3, b = blockIdx.y >> 2;
  const int s0 = st * 32;
  const int t = threadIdx.x;
  const int ls = t >> 3;               // local s 0..31
  const int ch = (t & 7) * 2;          // 16B-chunk pair
  const unsigned short* src = qkv + (size_t)(b * 2048 + s0 + ls) * 3072 + 2560 + kvh * 128 + ch * 8;
  u16x8 a0 = *reinterpret_cast<const u16x8*>(src);
  u16x8 a1 = *reinterpret_cast<const u16x8*>(src + 8);
  *reinterpret_cast<u16x8*>(&T[ls][ch * 8])     = a0;
  *reinterpret_cast<u16x8*>(&T[ls][ch * 8 + 8]) = a1;
  float* nv = newv + (size_t)(b * 2048 + s0 + ls) * 512 + kvh * 128 + ch * 8;
  float4 f0, f1, f2, f3;
  f0.x = b2f(a0[0]); f0.y = b2f(a0[1]); f0.z = b2f(a0[2]); f0.w = b2f(a0[3]);
  f1.x = b2f(a0[4]); f1.y = b2f(a0[5]); f1.z = b2f(a0[6]); f1.w = b2f(a0[7]);
  f2.x = b2f(a1[0]); f2.y = b2f(a1[1]); f2.z = b2f(a1[2]); f2.w = b2f(a1[3]);
  f3.x = b2f(a1[4]); f3.y = b2f(a1[5]); f3.z = b2f(a1[6]); f3.w = b2f(a1[7]);
  reinterpret_cast<float4*>(nv)[0] = f0;
  reinterpret_cast<float4*>(nv)[1] = f1;
  reinterpret_cast<float4*>(nv)[2] = f2;
  reinterpret_cast<float4*>(nv)[3] = f3;
  __syncthreads();
  const int d = t >> 1, half = t & 1;
  unsigned short* dst = vt + ((size_t)(b * 4 + kvh) * 128 + d) * 2048 + s0 + half * 16;
  u16x8 o0, o1;
#pragma unroll
  for (int q = 0; q < 8; q++) {
    int slot = half * 16 + q;
    int kl = ((slot >> 2) & 1) * 16 + (slot >> 3) * 4 + (slot & 3);
    o0[q] = T[kl][d];
  }
#pragma unroll
  for (int q = 0; q < 8; q++) {
    int slot = half * 16 + 8 + q;
    int kl = ((slot >> 2) & 1) * 16 + (slot >> 3) * 4 + (slot & 3);
    o1[q] = T[kl][d];
  }
  reinterpret_cast<u16x8*>(dst)[0] = o0;
  reinterpret_cast<u16x8*>(dst)[1] = o1;
}

// ---------------- flash attention: block = (q-tile16, kvh, b), 4 waves = 4 heads
// KVBLK=32, LDS 32KB (2 buf x (8KB K + 8KB V)), XCD-pinned (kvh,b) = bx&7.
__global__ __launch_bounds__(256, 4) void attn_kernel(const unsigned short* __restrict__ qro,
                                                      const unsigned short* __restrict__ kro,
                                                      const unsigned short* __restrict__ vt,
                                                      unsigned short* __restrict__ out) {
  __shared__ unsigned short Ks[2][32 * 128];   // [kv][d], rows 256B, swizzled
  __shared__ unsigned short Vs[2][64 * 64];    // paired-d rows 128B, swizzled
  const int tid = threadIdx.x, lane = tid & 63, w = tid >> 6;
  const int kvhb = blockIdx.x & 7;             // XCD pin: same (kvh,b) -> same XCD
  const int kvh = kvhb & 3, b = kvhb >> 2;
  const int t = 127 - (blockIdx.x >> 3);       // heavy-first
  const int h = kvh * 4 + w;                   // wave = one q-head
  const int qbase = t * 16;
  const int fr = lane & 15, g = lane >> 4, fk = g * 8;
  const unsigned short* Kp = kro + (size_t)(b * 4 + kvh) * 2048 * 128;
  const unsigned short* Vtp = vt + (size_t)(b * 4 + kvh) * 128 * 2048;
  const unsigned short* Qp = qro + ((size_t)(b * 16 + h) * 2048 + qbase) * 128;

  bf16x8 qf[4];
#pragma unroll
  for (int kk = 0; kk < 4; kk++)
    qf[kk] = *reinterpret_cast<const bf16x8*>(Qp + fr * 128 + kk * 32 + fk);

  u16x8 onesu;
#pragma unroll
  for (int j = 0; j < 8; j++) onesu[j] = 0x3F80;  // bf16 1.0
  bf16x8 ones = __builtin_bit_cast(bf16x8, onesu);

  f32x4 o[8];
#pragma unroll
  for (int dt = 0; dt < 8; dt++) o[dt] = f32x4{0.f, 0.f, 0.f, 0.f};
  f32x4 dacc = f32x4{0.f, 0.f, 0.f, 0.f};
  const int qrow_s = qbase + fr;
  const int nfull = (qbase >= 31) ? ((qbase - 31) >> 5) + 1 : 0;
  const int niter = nfull + 1;

  const int krow = w * 8 + (lane >> 4);        // K stage rows (+j*4)
  const int kcol = lane & 15;
  const int vrow = w * 16 + (lane >> 3);       // V stage rows, paired-d (+j*8)
  const int vcol = lane & 7;

  auto stage = [&](int kv0, int buf) {
    unsigned short* Kb = &Ks[buf][0];
    unsigned short* Vb = &Vs[buf][0];
#pragma unroll
    for (int j = 0; j < 2; j++) {
      int r = krow + j * 4;
      glds16(Kp + (size_t)(kv0 + r) * 128 + ((kcol ^ (r & 7)) * 8),
             Kb + (w * 8 + j * 4) * 128);
    }
#pragma unroll
    for (int j = 0; j < 2; j++) {
      int r = vrow + j * 8;
      int u = vcol ^ (r & 7);
      int d = 2 * r + (u >> 2);
      glds16(Vtp + (size_t)d * 2048 + kv0 + (u & 3) * 8,
             Vb + (w * 16 + j * 8) * 64);
    }
  };

  auto step = [&](int kv0, bool mask, int buf) {
    const unsigned short* Kb = &Ks[buf][0];
    const unsigned short* Vb = &Vs[buf][0];
    f32x4 sc[2];
    sc[0] = sc[1] = f32x4{0.f, 0.f, 0.f, 0.f};
    __builtin_amdgcn_s_setprio(1);
#pragma unroll
    for (int kk = 0; kk < 4; kk++) {
      int blk = ((kk * 4 + g) ^ (fr & 7)) * 8;
      bf16x8 ka0 = *reinterpret_cast<const bf16x8*>(Kb + (fr +  0) * 128 + blk);
      bf16x8 ka1 = *reinterpret_cast<const bf16x8*>(Kb + (fr + 16) * 128 + blk);
      sc[0] = __builtin_amdgcn_mfma_f32_16x16x32_bf16(ka0, qf[kk], sc[0], 0, 0, 0);
      sc[1] = __builtin_amdgcn_mfma_f32_16x16x32_bf16(ka1, qf[kk], sc[1], 0, 0, 0);
    }
    __builtin_amdgcn_s_setprio(0);
#pragma unroll
    for (int s = 0; s < 2; s++)
#pragma unroll
      for (int r = 0; r < 4; r++) {
        float v = sc[s][r];
        if (mask && (kv0 + 16 * s + 4 * g + r > qrow_s)) v = -1e30f;
        sc[s][r] = __builtin_amdgcn_exp2f(v);
      }
    u16x8 pau;
#pragma unroll
    for (int j = 0; j < 4; j++) {
      pau[j]     = f2b(sc[0][j]);
      pau[4 + j] = f2b(sc[1][j]);
    }
    bf16x8 pa = __builtin_bit_cast(bf16x8, pau);
    dacc = __builtin_amdgcn_mfma_f32_16x16x32_bf16(pa, ones, dacc, 0, 0, 0);
    __builtin_amdgcn_s_setprio(1);
#pragma unroll
    for (int dt = 0; dt < 8; dt++) {
      int jr = dt * 8 + (fr >> 1);
      int c = ((fr & 1) * 4 + g) ^ (fr >> 1);
      bf16x8 vf = *reinterpret_cast<const bf16x8*>(Vb + jr * 64 + c * 8);
      o[dt] = __builtin_amdgcn_mfma_f32_16x16x32_bf16(pa, vf, o[dt], 0, 0, 0);
    }
    __builtin_amdgcn_s_setprio(0);
  };

  stage(0, 0);
  int buf = 0;
  for (int i = 0; i < niter; i++) {
    __syncthreads();                 // tile i staged; prior reads of buf^1 done
    if (i + 1 < niter) stage((i + 1) * 32, buf ^ 1);
    step(i * 32, i == nfull, buf);
    buf ^= 1;
  }

#pragma unroll
  for (int r = 0; r < 4; r++) {
    float inv = 1.0f / dacc[r];
    int qrow = qbase + g * 4 + r;
    size_t rowoff = ((size_t)b * 2048 + qrow) * 2048 + (size_t)h * 128;
#pragma unroll
    for (int dt = 0; dt < 8; dt++)
      out[rowoff + dt * 16 + fr] = f2b(o[dt][r] * inv);
  }
}

// ---------------- launch ---------------------------------------------------
extern "C" void kernel_launch(void* const* d_in, const int* in_sizes, int n_in,
                              void* d_out, int out_size, void* d_ws, size_t ws_size,
                              hipStream_t stream) {
  const float* x  = (const float*)d_in[0];
  const float* wq = (const float*)d_in[1];
  const float* wk = (const float*)d_in[2];
  const float* wv = (const float*)d_in[3];
  const float* wo = (const float*)d_in[4];
  const float* freqs = (const float*)d_in[5];

  char* ws = (char*)d_ws;
  unsigned short* xb    = (unsigned short*)(ws);             // 16 MB, reused as attn out
  unsigned short* attn  = xb;
  unsigned short* wqkvb = (unsigned short*)(ws + 16777216);  // [3072][2048] bf16
  unsigned short* wob   = (unsigned short*)(ws + 29360128);
  unsigned short* qkv   = (unsigned short*)(ws + 37748736);  // [4096][3072] bf16
  unsigned short* qro   = (unsigned short*)(ws + 62914560);
  unsigned short* kro   = (unsigned short*)(ws + 79691776);
  unsigned short* vt    = (unsigned short*)(ws + 83886080);

  float* out_o = (float*)d_out;
  float* out_k = (float*)d_out + 8388608;
  float* out_v = (float*)d_out + 10485760;

  cvt_fused<<<9216, 256, 0, stream>>>(x, wq, wk, wv, wo, xb, wqkvb, wob);

  gemm_lds<0><<<dim3(24, 32), 256, 0, stream>>>(xb, wqkvb, qkv, 4096, 3072, 2048);

  rope_kernel<<<20480, 256, 0, stream>>>(qkv, freqs, qro, kro, out_k);
  vtrans_kernel<<<dim3(64, 8), 256, 0, stream>>>(qkv, vt, out_v);

  attn_kernel<<<1024, 256, 0, stream>>>(qro, kro, vt, attn);

  gemm_lds<1><<<dim3(16, 32), 256, 0, stream>>>(attn, wob, out_o, 4096, 2048, 2048);
}